// Round 1
// baseline (46.113 us; speedup 1.0000x reference)
//
#include <hip/hip_runtime.h>

#define DIM   1024
#define BATCH 8
#define SEQ   2048
#define SCHUNKS 16
#define ROWS_PER_CHUNK (SEQ / SCHUNKS)   // 128
#define LN_EPS 1e-5f

// ---------------------------------------------------------------------------
// Stage 1a: partial column sums of x over s.
// grid (DIM/256, BATCH, SCHUNKS), block 256.
// partial[c][b][e] = sum_{s in chunk c} x[b,s,e]
// ---------------------------------------------------------------------------
__global__ __launch_bounds__(256) void k_partial_colsum(
    const float* __restrict__ x, float* __restrict__ partial) {
  int e = blockIdx.x * 256 + threadIdx.x;
  int b = blockIdx.y;
  int c = blockIdx.z;
  const float* base = x + ((size_t)b * SEQ + (size_t)c * ROWS_PER_CHUNK) * DIM + e;
  float acc = 0.f;
#pragma unroll 8
  for (int s = 0; s < ROWS_PER_CHUNK; ++s) acc += base[(size_t)s * DIM];
  partial[((size_t)c * BATCH + b) * DIM + e] = acc;
}

// Stage 1b: finish column sum. grid (BATCH*DIM/256), block 256.
__global__ __launch_bounds__(256) void k_finish_colsum(
    const float* __restrict__ partial, float* __restrict__ xsum) {
  int i = blockIdx.x * 256 + threadIdx.x;  // over BATCH*DIM
  float acc = 0.f;
#pragma unroll
  for (int c = 0; c < SCHUNKS; ++c) acc += partial[(size_t)c * BATCH * DIM + i];
  xsum[i] = acc;
}

// ---------------------------------------------------------------------------
// Stage 2: batched GEMV, one wave per output element.
// out[b,d] = sum_e in[b,e] * W[d,e] (+ bias[d])
// grid (BATCH*DIM/4), block 256 (4 waves).
// ---------------------------------------------------------------------------
__global__ __launch_bounds__(256) void k_gemv(
    const float* __restrict__ vin, const float* __restrict__ W,
    const float* __restrict__ bias, float* __restrict__ vout) {
  int wave = threadIdx.x >> 6;
  int lane = threadIdx.x & 63;
  int o = blockIdx.x * 4 + wave;          // 0 .. BATCH*DIM-1
  int b = o >> 10;                        // DIM = 1024
  int d = o & (DIM - 1);
  const float* in = vin + (size_t)b * DIM;
  const float* w  = W + (size_t)d * DIM;
  float acc = 0.f;
#pragma unroll 4
  for (int e = lane; e < DIM; e += 64) acc += in[e] * w[e];
#pragma unroll
  for (int off = 32; off; off >>= 1) acc += __shfl_xor(acc, off, 64);
  if (lane == 0) {
    float r = acc;
    if (bias) r += bias[d];
    vout[o] = r;
  }
}

// ---------------------------------------------------------------------------
// Stage 3: out[b,s,:] = LayerNorm(x[b,s,:] + z[b,:]) * gamma + beta
// grid (BATCH*SEQ), block 256; each thread handles one float4 (4 elems).
// ---------------------------------------------------------------------------
__global__ __launch_bounds__(256) void k_residual_ln(
    const float* __restrict__ x, const float* __restrict__ z,
    const float* __restrict__ gamma, const float* __restrict__ beta,
    float* __restrict__ out) {
  int row = blockIdx.x;      // 0 .. BATCH*SEQ-1
  int b   = row >> 11;       // SEQ = 2048
  int t   = threadIdx.x;

  const float4* xr = (const float4*)(x + (size_t)row * DIM);
  const float4* zr = (const float4*)(z + (size_t)b * DIM);
  float4 xv = xr[t];
  float4 zv = zr[t];
  float4 h;
  h.x = xv.x + zv.x; h.y = xv.y + zv.y; h.z = xv.z + zv.z; h.w = xv.w + zv.w;

  float sum = h.x + h.y + h.z + h.w;
  float ss  = h.x * h.x + h.y * h.y + h.z * h.z + h.w * h.w;
#pragma unroll
  for (int off = 32; off; off >>= 1) {
    sum += __shfl_xor(sum, off, 64);
    ss  += __shfl_xor(ss,  off, 64);
  }

  __shared__ float s_sum[4], s_ss[4];
  int wave = t >> 6, lane = t & 63;
  if (lane == 0) { s_sum[wave] = sum; s_ss[wave] = ss; }
  __syncthreads();
  sum = s_sum[0] + s_sum[1] + s_sum[2] + s_sum[3];
  ss  = s_ss[0]  + s_ss[1]  + s_ss[2]  + s_ss[3];

  const float inv = 1.0f / (float)DIM;
  float mu  = sum * inv;
  float var = ss * inv - mu * mu;
  float rs  = rsqrtf(var + LN_EPS);

  float4 g  = ((const float4*)gamma)[t];
  float4 be = ((const float4*)beta)[t];
  float4 o;
  o.x = (h.x - mu) * rs * g.x + be.x;
  o.y = (h.y - mu) * rs * g.y + be.y;
  o.z = (h.z - mu) * rs * g.z + be.z;
  o.w = (h.w - mu) * rs * g.w + be.w;
  ((float4*)out)[(size_t)row * (DIM / 4) + t] = o;
}

extern "C" void kernel_launch(void* const* d_in, const int* in_sizes, int n_in,
                              void* d_out, int out_size, void* d_ws, size_t ws_size,
                              hipStream_t stream) {
  const float* x     = (const float*)d_in[0];   // [B, S, D]
  const float* w_qkv = (const float*)d_in[1];   // [3D, D]
  const float* w_fc  = (const float*)d_in[2];   // [D, D]
  const float* b_fc  = (const float*)d_in[3];   // [D]
  const float* gamma = (const float*)d_in[4];   // [D]
  const float* beta  = (const float*)d_in[5];   // [D]
  float* out = (float*)d_out;

  // workspace layout (floats)
  float* ws      = (float*)d_ws;
  float* partial = ws;                                   // SCHUNKS*B*D
  float* xsum    = partial + (size_t)SCHUNKS * BATCH * DIM;  // B*D
  float* vsum    = xsum + (size_t)BATCH * DIM;               // B*D
  float* z       = vsum + (size_t)BATCH * DIM;               // B*D

  const float* w_v = w_qkv + (size_t)2 * DIM * DIM;  // rows [2D, 3D) of w_qkv

  // 1) xsum[b,e] = sum_s x[b,s,e]
  dim3 g1(DIM / 256, BATCH, SCHUNKS);
  hipLaunchKernelGGL(k_partial_colsum, g1, dim3(256), 0, stream, x, partial);
  hipLaunchKernelGGL(k_finish_colsum, dim3(BATCH * DIM / 256), dim3(256), 0,
                     stream, partial, xsum);

  // 2) vsum = xsum @ Wv^T ; z = vsum @ Wfc^T + b_fc
  hipLaunchKernelGGL(k_gemv, dim3(BATCH * DIM / 4), dim3(256), 0, stream,
                     xsum, w_v, (const float*)nullptr, vsum);
  hipLaunchKernelGGL(k_gemv, dim3(BATCH * DIM / 4), dim3(256), 0, stream,
                     vsum, w_fc, b_fc, z);

  // 3) out = LN(x + z) * gamma + beta
  hipLaunchKernelGGL(k_residual_ln, dim3(BATCH * SEQ), dim3(256), 0, stream,
                     x, z, gamma, beta, out);
}